// Round 3
// baseline (133.970 us; speedup 1.0000x reference)
//
#include <hip/hip_runtime.h>

// SVDLayer: per-batch Kabsch rotation (no reflection fix).
// r_est = V U^T = K^{-1/2} H^T with K = H^T H (SPD).
// K^{-1/2} via fp32 Newton-Schulz (K ~ 1e6*(I+E), ||E||~0.1 -> quadratic).
//
// Structure: ONE WAVE PER BATCH. 64 lanes x 16 points, 24 float4 loads
// hoisted per lane (384B in flight), single 64-wide shuffle reduction of
// 15 partial sums, lane-0 fp32 3x3 tail, float4 stores.

constexpr int NPTS  = 1024;
constexpr int WAVES = 4;            // waves (=batches) per block
constexpr int THREADS = WAVES * 64;

__global__ __launch_bounds__(THREADS) void svd_layer_kernel(
    const float* __restrict__ cors,
    const float* __restrict__ p_src,
    float* __restrict__ out,
    int B)
{
    const int wave = threadIdx.x >> 6;
    const int lane = threadIdx.x & 63;
    const int b    = blockIdx.x * WAVES + wave;
    if (b >= B) return;

    const size_t base4 = (size_t)b * (NPTS * 3 / 4);   // float4 index of batch start
    const float4* s4 = reinterpret_cast<const float4*>(p_src) + base4 + lane * 12;
    const float4* c4 = reinterpret_cast<const float4*>(cors)  + base4 + lane * 12;

    // hoist all loads: 16 points/lane = 12 float4 src + 12 float4 cors
    float4 sv[12], cv[12];
    #pragma unroll
    for (int m = 0; m < 12; ++m) sv[m] = s4[m];
    #pragma unroll
    for (int m = 0; m < 12; ++m) cv[m] = c4[m];

    // 15 partials: Σsrc(3), Σpred(3), Σ src_i*pred_j (9)
    float acc[15];
    #pragma unroll
    for (int i = 0; i < 15; ++i) acc[i] = 0.f;

    #pragma unroll
    for (int g = 0; g < 4; ++g) {
        const float4 t0 = sv[g*3+0], t1 = sv[g*3+1], t2 = sv[g*3+2];
        const float4 u0 = cv[g*3+0], u1 = cv[g*3+1], u2 = cv[g*3+2];
        // unpack [x y z x][y z x y][z x y z] -> 4 points
        const float sx[4] = {t0.x, t0.w, t1.z, t2.y};
        const float sy[4] = {t0.y, t1.x, t1.w, t2.z};
        const float sz[4] = {t0.z, t1.y, t2.x, t2.w};
        const float px[4] = {sx[0]+u0.x, sx[1]+u0.w, sx[2]+u1.z, sx[3]+u2.y};
        const float py[4] = {sy[0]+u0.y, sy[1]+u1.x, sy[2]+u1.w, sy[3]+u2.z};
        const float pz[4] = {sz[0]+u0.z, sz[1]+u1.y, sz[2]+u2.x, sz[3]+u2.w};
        #pragma unroll
        for (int k = 0; k < 4; ++k) {
            acc[0]  += sx[k]; acc[1]  += sy[k]; acc[2]  += sz[k];
            acc[3]  += px[k]; acc[4]  += py[k]; acc[5]  += pz[k];
            acc[6]  += sx[k]*px[k]; acc[7]  += sx[k]*py[k]; acc[8]  += sx[k]*pz[k];
            acc[9]  += sy[k]*px[k]; acc[10] += sy[k]*py[k]; acc[11] += sy[k]*pz[k];
            acc[12] += sz[k]*px[k]; acc[13] += sz[k]*py[k]; acc[14] += sz[k]*pz[k];
        }
    }

    // single 64-lane butterfly reduce (no LDS, no barrier)
    #pragma unroll
    for (int off = 32; off > 0; off >>= 1) {
        #pragma unroll
        for (int i = 0; i < 15; ++i) acc[i] += __shfl_down(acc[i], off, 64);
    }

    if (lane != 0) return;

    // -------- lane 0: fp32 3x3 tail --------
    const float invN = 1.0f / (float)NPTS;
    const float cs[3] = {acc[0]*invN, acc[1]*invN, acc[2]*invN};
    const float cp[3] = {acc[3]*invN, acc[4]*invN, acc[5]*invN};

    float Hm[3][3];
    #pragma unroll
    for (int i = 0; i < 3; ++i)
        #pragma unroll
        for (int j = 0; j < 3; ++j)
            Hm[i][j] = acc[6 + i*3 + j] - (float)NPTS * cs[i] * cp[j];

    // K = H^T H (SPD)
    float K[3][3];
    #pragma unroll
    for (int i = 0; i < 3; ++i)
        #pragma unroll
        for (int j = 0; j < 3; ++j)
            K[i][j] = Hm[0][i]*Hm[0][j] + Hm[1][i]*Hm[1][j] + Hm[2][i]*Hm[2][j];

    // normalize: A = K / (tr/3), eigenvalues ~ 1
    const float tr3 = (K[0][0] + K[1][1] + K[2][2]) * (1.0f/3.0f);
    const float is  = 1.0f / fmaxf(tr3, 1e-30f);

    float Y[3][3], Z[3][3];
    #pragma unroll
    for (int i = 0; i < 3; ++i)
        #pragma unroll
        for (int j = 0; j < 3; ++j) {
            Y[i][j] = K[i][j] * is;
            Z[i][j] = (i == j) ? 1.0f : 0.0f;
        }

    // coupled Newton-Schulz: Y->A^{1/2}, Z->A^{-1/2}
    #pragma unroll
    for (int it = 0; it < 6; ++it) {
        float W[3][3];   // T = 1.5I - 0.5*Z*Y
        #pragma unroll
        for (int i = 0; i < 3; ++i)
            #pragma unroll
            for (int j = 0; j < 3; ++j) {
                float w = Z[i][0]*Y[0][j] + Z[i][1]*Y[1][j] + Z[i][2]*Y[2][j];
                W[i][j] = ((i == j) ? 1.5f : 0.0f) - 0.5f * w;
            }
        float Yn[3][3], Zn[3][3];
        #pragma unroll
        for (int i = 0; i < 3; ++i)
            #pragma unroll
            for (int j = 0; j < 3; ++j) {
                Yn[i][j] = Y[i][0]*W[0][j] + Y[i][1]*W[1][j] + Y[i][2]*W[2][j];
                Zn[i][j] = W[i][0]*Z[0][j] + W[i][1]*Z[1][j] + W[i][2]*Z[2][j];
            }
        #pragma unroll
        for (int i = 0; i < 3; ++i)
            #pragma unroll
            for (int j = 0; j < 3; ++j) { Y[i][j] = Yn[i][j]; Z[i][j] = Zn[i][j]; }
    }

    // M = K^{-1/2} = Z / sqrt(tr3);  R = M * H^T
    const float rs = rsqrtf(fmaxf(tr3, 1e-30f));
    float R[3][3];
    #pragma unroll
    for (int i = 0; i < 3; ++i)
        #pragma unroll
        for (int j = 0; j < 3; ++j)
            R[i][j] = (Z[i][0]*Hm[j][0] + Z[i][1]*Hm[j][1] + Z[i][2]*Hm[j][2]) * rs;

    const float t0 = cp[0] - (R[0][0]*cs[0] + R[0][1]*cs[1] + R[0][2]*cs[2]);
    const float t1 = cp[1] - (R[1][0]*cs[0] + R[1][1]*cs[1] + R[1][2]*cs[2]);
    const float t2 = cp[2] - (R[2][0]*cs[0] + R[2][1]*cs[1] + R[2][2]*cs[2]);

    float4* o4 = reinterpret_cast<float4*>(out + (size_t)b * 16);
    o4[0] = make_float4(R[0][0], R[0][1], R[0][2], t0);
    o4[1] = make_float4(R[1][0], R[1][1], R[1][2], t1);
    o4[2] = make_float4(R[2][0], R[2][1], R[2][2], t2);
    o4[3] = make_float4(0.f, 0.f, 0.f, 1.f);
}

extern "C" void kernel_launch(void* const* d_in, const int* in_sizes, int n_in,
                              void* d_out, int out_size, void* d_ws, size_t ws_size,
                              hipStream_t stream)
{
    const float* cors  = (const float*)d_in[0];
    const float* p_src = (const float*)d_in[1];
    float* out = (float*)d_out;
    const int B = in_sizes[0] / (NPTS * 3);        // 4096
    const int grid = (B + WAVES - 1) / WAVES;      // 1024
    hipLaunchKernelGGL(svd_layer_kernel, dim3(grid), dim3(THREADS), 0, stream,
                       cors, p_src, out, B);
}

// Round 4
// 118.687 us; speedup vs baseline: 1.1288x; 1.1288x over previous
//
#include <hip/hip_runtime.h>

// SVDLayer: per-batch Kabsch rotation (no reflection fix).
// r_est = V U^T = K^{-1/2} H^T, K = H^T H (SPD), K^{-1/2} via fp32 Newton-Schulz.
//
// R4 structure: one 256-thread block per batch.
//  - COALESCED global->LDS staging: thread t loads float4 [t+256m] (1KiB/instr/wave)
//  - per-point unpack read from LDS (48B lane stride -> conflict-free-ish)
//  - wave butterfly reduce + cross-wave LDS combine
//  - thread-0 fp32 Newton-Schulz 3x3 tail (verified absmax 3e-5)

constexpr int NPTS    = 1024;
constexpr int THREADS = 256;
constexpr int NF4     = NPTS * 3 / 4;      // 768 float4 per batch per array

__global__ __launch_bounds__(THREADS) void svd_layer_kernel(
    const float* __restrict__ cors,
    const float* __restrict__ p_src,
    float* __restrict__ out)
{
    __shared__ float4 lds_s[NF4];
    __shared__ float4 lds_c[NF4];
    __shared__ float  red[4][15];

    const int b = blockIdx.x;
    const int t = threadIdx.x;
    const int wave = t >> 6, lane = t & 63;

    const float4* s4 = reinterpret_cast<const float4*>(p_src) + (size_t)b * NF4;
    const float4* c4 = reinterpret_cast<const float4*>(cors)  + (size_t)b * NF4;

    // coalesced staging: 6 x 1KiB-per-wave loads
    float4 a0 = s4[t], a1 = s4[t + 256], a2 = s4[t + 512];
    float4 b0 = c4[t], b1 = c4[t + 256], b2 = c4[t + 512];
    lds_s[t] = a0; lds_s[t + 256] = a1; lds_s[t + 512] = a2;
    lds_c[t] = b0; lds_c[t + 256] = b1; lds_c[t + 512] = b2;
    __syncthreads();

    // per-point view: thread t owns 4 points = 3 consecutive float4s
    const float4 t0 = lds_s[t*3+0], t1 = lds_s[t*3+1], t2 = lds_s[t*3+2];
    const float4 u0 = lds_c[t*3+0], u1 = lds_c[t*3+1], u2 = lds_c[t*3+2];

    // unpack [x y z x][y z x y][z x y z] -> 4 points
    const float sx[4] = {t0.x, t0.w, t1.z, t2.y};
    const float sy[4] = {t0.y, t1.x, t1.w, t2.z};
    const float sz[4] = {t0.z, t1.y, t2.x, t2.w};
    const float px[4] = {sx[0]+u0.x, sx[1]+u0.w, sx[2]+u1.z, sx[3]+u2.y};
    const float py[4] = {sy[0]+u0.y, sy[1]+u1.x, sy[2]+u1.w, sy[3]+u2.z};
    const float pz[4] = {sz[0]+u0.z, sz[1]+u1.y, sz[2]+u2.x, sz[3]+u2.w};

    // 15 partials: Σsrc(3), Σpred(3), Σ src_i*pred_j (9)
    float acc[15];
    #pragma unroll
    for (int i = 0; i < 15; ++i) acc[i] = 0.f;
    #pragma unroll
    for (int k = 0; k < 4; ++k) {
        acc[0]  += sx[k]; acc[1]  += sy[k]; acc[2]  += sz[k];
        acc[3]  += px[k]; acc[4]  += py[k]; acc[5]  += pz[k];
        acc[6]  += sx[k]*px[k]; acc[7]  += sx[k]*py[k]; acc[8]  += sx[k]*pz[k];
        acc[9]  += sy[k]*px[k]; acc[10] += sy[k]*py[k]; acc[11] += sy[k]*pz[k];
        acc[12] += sz[k]*px[k]; acc[13] += sz[k]*py[k]; acc[14] += sz[k]*pz[k];
    }

    // 64-lane butterfly reduce
    #pragma unroll
    for (int off = 32; off > 0; off >>= 1) {
        #pragma unroll
        for (int i = 0; i < 15; ++i) acc[i] += __shfl_down(acc[i], off, 64);
    }

    if (lane == 0) {
        #pragma unroll
        for (int i = 0; i < 15; ++i) red[wave][i] = acc[i];
    }
    __syncthreads();
    if (t != 0) return;

    // -------- thread 0: fp32 3x3 tail --------
    float S[15];
    #pragma unroll
    for (int i = 0; i < 15; ++i)
        S[i] = red[0][i] + red[1][i] + red[2][i] + red[3][i];

    const float invN = 1.0f / (float)NPTS;
    const float cs[3] = {S[0]*invN, S[1]*invN, S[2]*invN};
    const float cp[3] = {S[3]*invN, S[4]*invN, S[5]*invN};

    float Hm[3][3];
    #pragma unroll
    for (int i = 0; i < 3; ++i)
        #pragma unroll
        for (int j = 0; j < 3; ++j)
            Hm[i][j] = S[6 + i*3 + j] - (float)NPTS * cs[i] * cp[j];

    // K = H^T H (SPD)
    float K[3][3];
    #pragma unroll
    for (int i = 0; i < 3; ++i)
        #pragma unroll
        for (int j = 0; j < 3; ++j)
            K[i][j] = Hm[0][i]*Hm[0][j] + Hm[1][i]*Hm[1][j] + Hm[2][i]*Hm[2][j];

    const float tr3 = (K[0][0] + K[1][1] + K[2][2]) * (1.0f/3.0f);
    const float is  = 1.0f / fmaxf(tr3, 1e-30f);

    float Y[3][3], Z[3][3];
    #pragma unroll
    for (int i = 0; i < 3; ++i)
        #pragma unroll
        for (int j = 0; j < 3; ++j) {
            Y[i][j] = K[i][j] * is;
            Z[i][j] = (i == j) ? 1.0f : 0.0f;
        }

    // coupled Newton-Schulz: Y->A^{1/2}, Z->A^{-1/2}
    #pragma unroll
    for (int it = 0; it < 6; ++it) {
        float W[3][3];
        #pragma unroll
        for (int i = 0; i < 3; ++i)
            #pragma unroll
            for (int j = 0; j < 3; ++j) {
                float w = Z[i][0]*Y[0][j] + Z[i][1]*Y[1][j] + Z[i][2]*Y[2][j];
                W[i][j] = ((i == j) ? 1.5f : 0.0f) - 0.5f * w;
            }
        float Yn[3][3], Zn[3][3];
        #pragma unroll
        for (int i = 0; i < 3; ++i)
            #pragma unroll
            for (int j = 0; j < 3; ++j) {
                Yn[i][j] = Y[i][0]*W[0][j] + Y[i][1]*W[1][j] + Y[i][2]*W[2][j];
                Zn[i][j] = W[i][0]*Z[0][j] + W[i][1]*Z[1][j] + W[i][2]*Z[2][j];
            }
        #pragma unroll
        for (int i = 0; i < 3; ++i)
            #pragma unroll
            for (int j = 0; j < 3; ++j) { Y[i][j] = Yn[i][j]; Z[i][j] = Zn[i][j]; }
    }

    // R = (Z/sqrt(tr3)) * H^T ; t = cp - R cs
    const float rs = rsqrtf(fmaxf(tr3, 1e-30f));
    float R[3][3];
    #pragma unroll
    for (int i = 0; i < 3; ++i)
        #pragma unroll
        for (int j = 0; j < 3; ++j)
            R[i][j] = (Z[i][0]*Hm[j][0] + Z[i][1]*Hm[j][1] + Z[i][2]*Hm[j][2]) * rs;

    const float tx = cp[0] - (R[0][0]*cs[0] + R[0][1]*cs[1] + R[0][2]*cs[2]);
    const float ty = cp[1] - (R[1][0]*cs[0] + R[1][1]*cs[1] + R[1][2]*cs[2]);
    const float tz = cp[2] - (R[2][0]*cs[0] + R[2][1]*cs[1] + R[2][2]*cs[2]);

    float4* o4 = reinterpret_cast<float4*>(out + (size_t)b * 16);
    o4[0] = make_float4(R[0][0], R[0][1], R[0][2], tx);
    o4[1] = make_float4(R[1][0], R[1][1], R[1][2], ty);
    o4[2] = make_float4(R[2][0], R[2][1], R[2][2], tz);
    o4[3] = make_float4(0.f, 0.f, 0.f, 1.f);
}

extern "C" void kernel_launch(void* const* d_in, const int* in_sizes, int n_in,
                              void* d_out, int out_size, void* d_ws, size_t ws_size,
                              hipStream_t stream)
{
    const float* cors  = (const float*)d_in[0];
    const float* p_src = (const float*)d_in[1];
    float* out = (float*)d_out;
    const int B = in_sizes[0] / (NPTS * 3);   // 4096
    hipLaunchKernelGGL(svd_layer_kernel, dim3(B), dim3(THREADS), 0, stream,
                       cors, p_src, out);
}